// Round 2
// baseline (566.537 us; speedup 1.0000x reference)
//
#include <hip/hip_runtime.h>

typedef __attribute__((ext_vector_type(8))) short bf16x8;
typedef __attribute__((ext_vector_type(4))) float f32x4;

#define NB 2048
#define NC 64
#define NH 256
#define ND 512
#define NG 768   // 3*NH
#define WIH_LD 576  // NC + ND

__device__ __forceinline__ unsigned short f2b(float f) {
  union { float f; unsigned u; } v; v.f = f;
  unsigned r = v.u + 0x7FFFu + ((v.u >> 16) & 1u);
  return (unsigned short)(r >> 16);
}
__device__ __forceinline__ float b2f(unsigned short h) {
  union { unsigned u; float f; } v; v.u = ((unsigned)h) << 16;
  return v.f;
}
__device__ __forceinline__ float sigf(float x) { return 1.0f / (1.0f + __expf(-x)); }
__device__ __forceinline__ float tanhf_(float x) { return 1.0f - 2.0f / (__expf(2.0f * x) + 1.0f); }

// ---------------- prep: bf16 conversions + Wp transpose ----------------
__global__ void k_prep(const float* __restrict__ X, const float* __restrict__ W_ih,
                       const float* __restrict__ W_hh,
                       unsigned short* __restrict__ Xb, unsigned short* __restrict__ Wxb,
                       unsigned short* __restrict__ Whb, float* __restrict__ WpT)
{
  const int stride = gridDim.x * blockDim.x;
  const int i0 = blockIdx.x * blockDim.x + threadIdx.x;
  for (int i = i0; i < NB * ND; i += stride) Xb[i] = f2b(X[i]);
  for (int i = i0; i < NG * ND; i += stride) {
    int r = i >> 9, k = i & (ND - 1);
    Wxb[i] = f2b(W_ih[r * WIH_LD + NC + k]);
  }
  for (int i = i0; i < NG * NH; i += stride) Whb[i] = f2b(W_hh[i]);
  for (int i = i0; i < NC * NG; i += stride) {
    int p = i / NG, g = i - p * NG;
    WpT[i] = W_ih[g * WIH_LD + p];
  }
}

// ---------------- gx = Xb @ Wxb^T + b_ih  (fp32 out) ----------------
__global__ __launch_bounds__(256) void k_gx(const unsigned short* __restrict__ Xb,
                                            const unsigned short* __restrict__ Wxb,
                                            const float* __restrict__ b_ih,
                                            float* __restrict__ gx)
{
  const int row0 = blockIdx.x * 64;
  const int col0 = blockIdx.y * 64;
  const int tid = threadIdx.x;
  const int w = tid >> 6, lane = tid & 63;
  const int l15 = lane & 15, lg = lane >> 4;
  const int col = col0 + w * 16 + l15;
  f32x4 acc[4] = {};
  for (int kk = 0; kk < 16; ++kk) {
    const int k0 = kk * 32 + lg * 8;
    bf16x8 b = *reinterpret_cast<const bf16x8*>(&Wxb[col * ND + k0]);
#pragma unroll
    for (int m = 0; m < 4; ++m) {
      const int row = row0 + m * 16 + l15;
      bf16x8 a = *reinterpret_cast<const bf16x8*>(&Xb[row * ND + k0]);
      acc[m] = __builtin_amdgcn_mfma_f32_16x16x32_bf16(a, b, acc[m], 0, 0, 0);
    }
  }
  const float bi = b_ih[col];
#pragma unroll
  for (int m = 0; m < 4; ++m)
#pragma unroll
    for (int q = 0; q < 4; ++q) {
      const int row = row0 + m * 16 + lg * 4 + q;
      gx[row * NG + col] = acc[m][q] + bi;
    }
}

// ---------------- fused GRU chain + logits ----------------
// grid: (64 batch-tiles of 32 rows, 64 classes), 256 threads (4 waves)
// Static LDS only (~40 KB): h double buffer (bf16, XOR-swizzled) + wp/bhh + reduce
__global__ __launch_bounds__(256) void k_chain(const float* __restrict__ Y,
                                               const float* __restrict__ gx,
                                               const unsigned short* __restrict__ Whb,
                                               const float* __restrict__ WpT,
                                               const float* __restrict__ b_hh,
                                               const float* __restrict__ W_out,
                                               const float* __restrict__ b_out,
                                               float* __restrict__ out)
{
  __shared__ unsigned short hb[2][32 * NH];   // 2 * 16384 B
  __shared__ float wp_s[NG];                  // 3072 B
  __shared__ float bhh_s[NG];                 // 3072 B
  __shared__ float red[256];                  // 1024 B

  const int c = blockIdx.y;
  const int row0 = blockIdx.x * 32;
  const int tid = threadIdx.x;
  const int nsteps = (c == 0) ? 1 : (c < 3 ? c : 3);
  const float myv = (c == 0) ? 0.0f : 1.0f;
  const int pbase = (c == 0) ? 0 : (c - nsteps);

  for (int idx = tid; idx < NG; idx += 256) {
    bhh_s[idx] = b_hh[idx];
    wp_s[idx] = WpT[pbase * NG + idx];
  }
  __syncthreads();

  // ---- t = 0: h = 0 -> gh = b_hh, pure elementwise ----
  {
    const int j = tid;  // 0..255 (hidden index)
    const float wpr = wp_s[j], wpz = wp_s[NH + j], wpn = wp_s[2 * NH + j];
    const float bhr = bhh_s[j], bhz = bhh_s[NH + j], bhn = bhh_s[2 * NH + j];
    for (int i = 0; i < 32; ++i) {
      const int brow = row0 + i;
      const float yv = myv * Y[brow * NC + pbase];
      float gir = gx[brow * NG + j]          + yv * wpr;
      float giz = gx[brow * NG + NH + j]     + yv * wpz;
      float gin = gx[brow * NG + 2 * NH + j] + yv * wpn;
      float r = sigf(gir + bhr);
      float z = sigf(giz + bhz);
      float n = tanhf_(gin + r * bhn);
      float h = (1.0f - z) * n;
      hb[0][i * NH + (j ^ ((i & 7) << 3))] = f2b(h);
    }
  }

  // ---- t = 1 .. nsteps-1: MFMA gh = h @ W_hh^T, fused gate epilogue ----
  const int w = tid >> 6, lane = tid & 63;
  const int l15 = lane & 15, lg = lane >> 4;

  for (int t = 1; t < nsteps; ++t) {
    const int p = pbase + t;
    __syncthreads();
    for (int idx = tid; idx < NG; idx += 256) wp_s[idx] = WpT[p * NG + idx];
    __syncthreads();
    const unsigned short* hr = hb[(t + 1) & 1];
    unsigned short* hw = hb[t & 1];

    for (int jc = 0; jc < 4; ++jc) {
      const int j0 = jc * 64 + w * 16;
      const int colr = j0 + l15;
      f32x4 ar[2] = {}, az[2] = {}, an[2] = {};
      for (int kk = 0; kk < 8; ++kk) {
        const int k0 = kk * 32 + lg * 8;
        bf16x8 a[2];
#pragma unroll
        for (int m = 0; m < 2; ++m) {
          const int row = m * 16 + l15;
          a[m] = *reinterpret_cast<const bf16x8*>(&hr[row * NH + (k0 ^ ((row & 7) << 3))]);
        }
        bf16x8 br = *reinterpret_cast<const bf16x8*>(&Whb[colr * NH + k0]);
        bf16x8 bz = *reinterpret_cast<const bf16x8*>(&Whb[(NH + colr) * NH + k0]);
        bf16x8 bn = *reinterpret_cast<const bf16x8*>(&Whb[(2 * NH + colr) * NH + k0]);
#pragma unroll
        for (int m = 0; m < 2; ++m) {
          ar[m] = __builtin_amdgcn_mfma_f32_16x16x32_bf16(a[m], br, ar[m], 0, 0, 0);
          az[m] = __builtin_amdgcn_mfma_f32_16x16x32_bf16(a[m], bz, az[m], 0, 0, 0);
          an[m] = __builtin_amdgcn_mfma_f32_16x16x32_bf16(a[m], bn, an[m], 0, 0, 0);
        }
      }
      // epilogue: C/D layout col = lane&15, row = (lane>>4)*4 + reg  [m89-verified]
      const int jj = j0 + l15;
      const float wpr = wp_s[jj], wpz = wp_s[NH + jj], wpn = wp_s[2 * NH + jj];
      const float bhr = bhh_s[jj], bhz = bhh_s[NH + jj], bhn = bhh_s[2 * NH + jj];
#pragma unroll
      for (int m = 0; m < 2; ++m)
#pragma unroll
        for (int q = 0; q < 4; ++q) {
          const int row = m * 16 + lg * 4 + q;
          const int brow = row0 + row;
          const float yv = Y[brow * NC + p];
          float gir = gx[brow * NG + jj]          + yv * wpr;
          float giz = gx[brow * NG + NH + jj]     + yv * wpz;
          float gin = gx[brow * NG + 2 * NH + jj] + yv * wpn;
          float r = sigf(gir + ar[m][q] + bhr);
          float z = sigf(giz + az[m][q] + bhz);
          float n = tanhf_(gin + r * (an[m][q] + bhn));
          float hold = b2f(hr[row * NH + (jj ^ ((row & 7) << 3))]);
          float hnew = (1.0f - z) * n + z * hold;
          hw[row * NH + (jj ^ ((row & 7) << 3))] = f2b(hnew);
        }
    }
  }

  // ---- logits: out[b][c] = h . W_out[c] + b_out[c] ----
  __syncthreads();
  const unsigned short* hf = hb[(nsteps - 1) & 1];
  {
    const int row = tid >> 3, part = tid & 7;  // 8 threads per batch row
    float s = 0.0f;
#pragma unroll
    for (int v = 0; v < 4; ++v) {
      const int e0 = part * 32 + v * 8;
      const bf16x8 hv = *reinterpret_cast<const bf16x8*>(&hf[row * NH + (e0 ^ ((row & 7) << 3))]);
#pragma unroll
      for (int e = 0; e < 8; ++e)
        s += b2f((unsigned short)hv[e]) * W_out[c * NH + e0 + e];
    }
    red[tid] = s;
  }
  __syncthreads();
  if (tid < 32) {
    float tot = b_out[c];
#pragma unroll
    for (int e = 0; e < 8; ++e) tot += red[tid * 8 + e];
    out[(row0 + tid) * NC + c] = tot;
  }
}

extern "C" void kernel_launch(void* const* d_in, const int* in_sizes, int n_in,
                              void* d_out, int out_size, void* d_ws, size_t ws_size,
                              hipStream_t stream)
{
  const float* X     = (const float*)d_in[0];
  const float* Y     = (const float*)d_in[1];
  const float* W_ih  = (const float*)d_in[2];
  const float* W_hh  = (const float*)d_in[3];
  const float* b_ih  = (const float*)d_in[4];
  const float* b_hh  = (const float*)d_in[5];
  const float* W_out = (const float*)d_in[6];
  const float* b_out = (const float*)d_in[7];
  float* out = (float*)d_out;

  char* ws = (char*)d_ws;
  float*          gx  = (float*)ws;                         // 6291456 B
  unsigned short* Xb  = (unsigned short*)(ws + 6291456);    // 2097152 B
  unsigned short* Wxb = (unsigned short*)(ws + 8388608);    //  786432 B
  unsigned short* Whb = (unsigned short*)(ws + 9175040);    //  393216 B
  float*          WpT = (float*)(ws + 9568256);             //  196608 B

  k_prep<<<dim3(1024), dim3(256), 0, stream>>>(X, W_ih, W_hh, Xb, Wxb, Whb, WpT);
  k_gx<<<dim3(32, 12), dim3(256), 0, stream>>>(Xb, Wxb, b_ih, gx);
  k_chain<<<dim3(64, 64), dim3(256), 0, stream>>>(Y, gx, Whb, WpT, b_hh, W_out, b_out, out);
}